// Round 1
// baseline (1059.654 us; speedup 1.0000x reference)
//
#include <hip/hip_runtime.h>
#include <hip/hip_bf16.h>

#define N_NODES 50000
#define DIM 128
#define N_GRAPHS 64
#define E_RAW 800000
#define E_TOT 850000
#define NEG_SLOPE 0.2f

// ---------- helpers ----------
__device__ __forceinline__ unsigned enc_f32(float f) {
    unsigned u = __float_as_uint(f);
    return (u & 0x80000000u) ? ~u : (u | 0x80000000u);
}
__device__ __forceinline__ float dec_f32(unsigned v) {
    return (v & 0x80000000u) ? __uint_as_float(v ^ 0x80000000u) : __uint_as_float(~v);
}
#define ENC_NEG_INF 0x007FFFFFu  // enc_f32(-inf)

// ---------- init ----------
__global__ void zero_kernel(int* deg, int* fillc, float* pooled, int n) {
    int i = blockIdx.x * blockDim.x + threadIdx.x;
    if (i < n) { deg[i] = 0; fillc[i] = 0; }
    if (i < N_GRAPHS * DIM) pooled[i] = 0.f;
}

__global__ void init_ms_kernel(unsigned* menc, float* ssum, int n) {
    int i = blockIdx.x * blockDim.x + threadIdx.x;
    if (i < n) { menc[i] = ENC_NEG_INF; ssum[i] = 0.f; }
}

// ---------- CSR build ----------
__global__ void count_kernel(const int* __restrict__ ei, int* __restrict__ deg) {
    int e = blockIdx.x * blockDim.x + threadIdx.x;
    if (e >= E_TOT) return;
    int dst = (e < E_RAW) ? ei[E_RAW + e] : (e - E_RAW);
    atomicAdd(&deg[dst], 1);
}

__global__ void scan1_kernel(const int* __restrict__ deg, int* __restrict__ excl,
                             int* __restrict__ blksum, int n) {
    __shared__ int lds[256];
    int t = threadIdx.x;
    int i = blockIdx.x * 256 + t;
    int v = (i < n) ? deg[i] : 0;
    lds[t] = v;
    __syncthreads();
    int incl = v;
    for (int off = 1; off < 256; off <<= 1) {
        int y = (t >= off) ? lds[t - off] : 0;
        __syncthreads();
        incl += y;
        lds[t] = incl;
        __syncthreads();
    }
    if (i < n) excl[i] = incl - v;
    if (t == 255) blksum[blockIdx.x] = incl;
}

__global__ void scan2_kernel(int* __restrict__ blksum, int nblk) {
    __shared__ int lds[256];
    int t = threadIdx.x;
    int v = (t < nblk) ? blksum[t] : 0;
    lds[t] = v;
    __syncthreads();
    int incl = v;
    for (int off = 1; off < 256; off <<= 1) {
        int y = (t >= off) ? lds[t - off] : 0;
        __syncthreads();
        incl += y;
        lds[t] = incl;
        __syncthreads();
    }
    if (t < nblk) blksum[t] = incl - v;  // exclusive
}

__global__ void scan3_kernel(int* __restrict__ row_ptr, const int* __restrict__ blksum, int n) {
    int i = blockIdx.x * blockDim.x + threadIdx.x;
    if (i < n) row_ptr[i] += blksum[i >> 8];
    if (i == 0) row_ptr[n] = E_TOT;
}

__global__ void fill_kernel(const int* __restrict__ ei, const int* __restrict__ row_ptr,
                            int* __restrict__ fillc, int* __restrict__ csr_src,
                            int* __restrict__ csr_pos) {
    int e = blockIdx.x * blockDim.x + threadIdx.x;
    if (e >= E_TOT) return;
    int src, dst;
    if (e < E_RAW) { src = ei[e]; dst = ei[E_RAW + e]; }
    else           { src = dst = e - E_RAW; }
    int slot = row_ptr[dst] + atomicAdd(&fillc[dst], 1);
    csr_src[slot] = src;
    csr_pos[e] = slot;
}

// ---------- GEMM: H = X @ W  (X:[n,128], W:[128,128]) ----------
// block 256 threads (16x16), tile 128 rows x 128 cols, 8x8 per thread.
__global__ __launch_bounds__(256) void gemm_kernel(const float* __restrict__ X,
                                                   const float* __restrict__ W,
                                                   float* __restrict__ H, int nrows) {
    __shared__ float Wl[DIM][DIM];  // 64 KiB
    int t = threadIdx.x;
    for (int i = t; i < DIM * DIM / 4; i += 256)
        ((float4*)&Wl[0][0])[i] = ((const float4*)W)[i];
    __syncthreads();

    int tx = t & 15, ty = t >> 4;
    int row0 = blockIdx.x * 128 + ty * 8;
    int col0 = tx * 8;
    float acc[8][8];
#pragma unroll
    for (int r = 0; r < 8; ++r)
#pragma unroll
        for (int c = 0; c < 8; ++c) acc[r][c] = 0.f;

    for (int k = 0; k < DIM; k += 4) {
        float4 xr[8];
#pragma unroll
        for (int r = 0; r < 8; ++r) {
            int row = row0 + r;
            xr[r] = (row < nrows) ? *(const float4*)&X[row * DIM + k]
                                  : make_float4(0.f, 0.f, 0.f, 0.f);
        }
#pragma unroll
        for (int kk = 0; kk < 4; ++kk) {
            float w0[8];
#pragma unroll
            for (int c = 0; c < 8; ++c) w0[c] = Wl[k + kk][col0 + c];
#pragma unroll
            for (int r = 0; r < 8; ++r) {
                float xv = (kk == 0) ? xr[r].x : (kk == 1) ? xr[r].y : (kk == 2) ? xr[r].z : xr[r].w;
#pragma unroll
                for (int c = 0; c < 8; ++c) acc[r][c] = fmaf(xv, w0[c], acc[r][c]);
            }
        }
    }
#pragma unroll
    for (int r = 0; r < 8; ++r) {
        int row = row0 + r;
        if (row < nrows) {
#pragma unroll
            for (int c = 0; c < 8; c += 4) {
                *(float4*)&H[row * DIM + col0 + c] =
                    make_float4(acc[r][c], acc[r][c + 1], acc[r][c + 2], acc[r][c + 3]);
            }
        }
    }
}

// ---------- per-node attention dots ----------
__global__ void dots_kernel(const float* __restrict__ H, const float* __restrict__ asrc,
                            const float* __restrict__ adst, float* __restrict__ s1,
                            float* __restrict__ s2, int n) {
    int wid = (blockIdx.x * blockDim.x + threadIdx.x) >> 6;
    int lane = threadIdx.x & 63;
    if (wid >= n) return;
    float2 hv = *(const float2*)&H[wid * DIM + 2 * lane];
    float2 a1 = *(const float2*)&asrc[2 * lane];
    float2 a2 = *(const float2*)&adst[2 * lane];
    float v1 = hv.x * a1.x + hv.y * a1.y;
    float v2 = hv.x * a2.x + hv.y * a2.y;
    for (int off = 32; off; off >>= 1) {
        v1 += __shfl_down(v1, off);
        v2 += __shfl_down(v2, off);
    }
    if (lane == 0) { s1[wid] = v1; s2[wid] = v2; }
}

// ---------- edge pass 1: alpha + segment max ----------
__global__ void edge1_kernel(const int* __restrict__ ei, const float* __restrict__ s1,
                             const float* __restrict__ s2, float* __restrict__ alpha,
                             unsigned* __restrict__ menc) {
    int e = blockIdx.x * blockDim.x + threadIdx.x;
    if (e >= E_TOT) return;
    int src, dst;
    if (e < E_RAW) { src = ei[e]; dst = ei[E_RAW + e]; }
    else           { src = dst = e - E_RAW; }
    float a = s1[src] + s2[dst];
    a = (a > 0.f) ? a : NEG_SLOPE * a;
    alpha[e] = a;
    atomicMax(&menc[dst], enc_f32(a));
}

// ---------- edge pass 2: exp + segment sum + scatter into CSR order ----------
__global__ void edge2_kernel(const int* __restrict__ ei, const float* __restrict__ alpha,
                             const unsigned* __restrict__ menc, float* __restrict__ ssum,
                             const int* __restrict__ csr_pos, float* __restrict__ wcsr) {
    int e = blockIdx.x * blockDim.x + threadIdx.x;
    if (e >= E_TOT) return;
    int dst = (e < E_RAW) ? ei[E_RAW + e] : (e - E_RAW);
    float m = dec_f32(menc[dst]);
    float ev = __expf(alpha[e] - m);
    atomicAdd(&ssum[dst], ev);
    wcsr[csr_pos[e]] = ev;
}

// ---------- aggregation: one wave per dst node ----------
__global__ void agg_kernel(const float* __restrict__ H, const float* __restrict__ wcsr,
                           const int* __restrict__ csr_src, const int* __restrict__ row_ptr,
                           const float* __restrict__ ssum, const float* __restrict__ bias,
                           float* __restrict__ Xout, const int* __restrict__ batch,
                           float* __restrict__ pooled, int pool_flag, int n) {
    int wid = (blockIdx.x * blockDim.x + threadIdx.x) >> 6;
    int lane = threadIdx.x & 63;
    if (wid >= n) return;
    int beg = row_ptr[wid], end = row_ptr[wid + 1];
    float inv = 1.f / (ssum[wid] + 1e-16f);
    float2 acc = *(const float2*)&bias[2 * lane];
    for (int s = beg; s < end; ++s) {
        float w = wcsr[s] * inv;
        int sn = csr_src[s];
        float2 hv = *(const float2*)&H[sn * DIM + 2 * lane];
        acc.x = fmaf(w, hv.x, acc.x);
        acc.y = fmaf(w, hv.y, acc.y);
    }
    acc.x = fmaxf(acc.x, 0.f);
    acc.y = fmaxf(acc.y, 0.f);
    *(float2*)&Xout[wid * DIM + 2 * lane] = acc;
    if (pool_flag) {
        int g = batch[wid];
        atomicAdd(&pooled[g * DIM + 2 * lane], acc.x);
        atomicAdd(&pooled[g * DIM + 2 * lane + 1], acc.y);
    }
}

// ---------- final head: y[g] = pooled[g] . Wf + bf ----------
__global__ void final_kernel(const float* __restrict__ pooled, const float* __restrict__ Wf,
                             const float* __restrict__ bf, float* __restrict__ y) {
    int wid = (blockIdx.x * blockDim.x + threadIdx.x) >> 6;
    int lane = threadIdx.x & 63;
    if (wid >= N_GRAPHS) return;
    float2 p = *(const float2*)&pooled[wid * DIM + 2 * lane];
    float2 w = *(const float2*)&Wf[2 * lane];
    float v = p.x * w.x + p.y * w.y;
    for (int off = 32; off; off >>= 1) v += __shfl_down(v, off);
    if (lane == 0) y[wid] = v + bf[0];
}

extern "C" void kernel_launch(void* const* d_in, const int* in_sizes, int n_in,
                              void* d_out, int out_size, void* d_ws, size_t ws_size,
                              hipStream_t stream) {
    const float* x       = (const float*)d_in[0];
    const int*   ei      = (const int*)d_in[1];
    const int*   batch   = (const int*)d_in[2];
    const float* Ws      = (const float*)d_in[3];
    const float* att_src = (const float*)d_in[4];
    const float* att_dst = (const float*)d_in[5];
    const float* biases  = (const float*)d_in[6];
    const float* Wf      = (const float*)d_in[7];
    const float* bf      = (const float*)d_in[8];
    float* y = (float*)d_out;

    // workspace carve-up (256B aligned)
    char* p = (char*)d_ws;
    auto alloc = [&](size_t bytes) -> void* {
        void* r = (void*)p;
        p += (bytes + 255) & ~(size_t)255;
        return r;
    };
    float* xA      = (float*)alloc((size_t)N_NODES * DIM * 4);
    float* xB      = (float*)alloc((size_t)N_NODES * DIM * 4);
    float* h       = (float*)alloc((size_t)N_NODES * DIM * 4);
    float* alphab  = (float*)alloc((size_t)E_TOT * 4);
    float* wcsr    = (float*)alloc((size_t)E_TOT * 4);
    int*   csr_src = (int*)alloc((size_t)E_TOT * 4);
    int*   csr_pos = (int*)alloc((size_t)E_TOT * 4);
    int*   deg     = (int*)alloc((size_t)N_NODES * 4);
    int*   fillc   = (int*)alloc((size_t)N_NODES * 4);
    int*   row_ptr = (int*)alloc((size_t)(N_NODES + 1) * 4);
    int*   blksum  = (int*)alloc(256 * 4);
    unsigned* menc = (unsigned*)alloc((size_t)N_NODES * 4);
    float* ssum    = (float*)alloc((size_t)N_NODES * 4);
    float* s1      = (float*)alloc((size_t)N_NODES * 4);
    float* s2      = (float*)alloc((size_t)N_NODES * 4);
    float* pooled  = (float*)alloc((size_t)N_GRAPHS * DIM * 4);

    const int BN = 256;
    const int gN   = (N_NODES + BN - 1) / BN;        // 196
    const int gE   = (E_TOT + BN - 1) / BN;          // 3321
    const int gNW  = (N_NODES * 64 + BN - 1) / BN;   // 12500 (wave per node)
    const int nblk = gN;                             // scan blocks

    // CSR build (edges are layer-invariant)
    zero_kernel<<<gN, BN, 0, stream>>>(deg, fillc, pooled, N_NODES);
    count_kernel<<<gE, BN, 0, stream>>>(ei, deg);
    scan1_kernel<<<nblk, BN, 0, stream>>>(deg, row_ptr, blksum, N_NODES);
    scan2_kernel<<<1, BN, 0, stream>>>(blksum, nblk);
    scan3_kernel<<<gN, BN, 0, stream>>>(row_ptr, blksum, N_NODES);
    fill_kernel<<<gE, BN, 0, stream>>>(ei, row_ptr, fillc, csr_src, csr_pos);

    const float* xin = x;
    float* xout = xA;
    for (int l = 0; l < 3; ++l) {
        const float* W  = Ws + (size_t)l * DIM * DIM;
        const float* as = att_src + (size_t)l * DIM;
        const float* ad = att_dst + (size_t)l * DIM;
        const float* b  = biases + (size_t)l * DIM;

        init_ms_kernel<<<gN, BN, 0, stream>>>(menc, ssum, N_NODES);
        gemm_kernel<<<(N_NODES + 127) / 128, BN, 0, stream>>>(xin, W, h, N_NODES);
        dots_kernel<<<gNW, BN, 0, stream>>>(h, as, ad, s1, s2, N_NODES);
        edge1_kernel<<<gE, BN, 0, stream>>>(ei, s1, s2, alphab, menc);
        edge2_kernel<<<gE, BN, 0, stream>>>(ei, alphab, menc, ssum, csr_pos, wcsr);
        agg_kernel<<<gNW, BN, 0, stream>>>(h, wcsr, csr_src, row_ptr, ssum, b, xout,
                                           batch, pooled, (l == 2) ? 1 : 0, N_NODES);
        xin = xout;
        xout = (l == 0) ? xB : xA;
    }

    final_kernel<<<(N_GRAPHS * 64 + BN - 1) / BN, BN, 0, stream>>>(pooled, Wf, bf, y);
}